// Round 12
// baseline (293.237 us; speedup 1.0000x reference)
//
#include <hip/hip_runtime.h>
#include <math.h>

// Problem constants (fixed by the reference)
#define TT 32
#define NN 20000
#define FF 128
#define HH 128
#define CC 10
#define RPB 32          // rows per block (20000/32 = 625 blocks exactly)
#define NTHREADS 256    // 4 waves; each wave owns a 32-col N-stripe (32x32 MFMA)

typedef __attribute__((ext_vector_type(8))) _Float16 f16x8;   // 4 VGPRs
typedef __attribute__((ext_vector_type(4))) _Float16 f16x4;   // 2 VGPRs
typedef __attribute__((ext_vector_type(4))) float  f32x4;     // 16x16 MFMA acc
typedef __attribute__((ext_vector_type(16))) float f32x16;    // 32x32 MFMA acc

// d_ws layout (f16 elements):
//   [0, 32768)       Whi[kg][c][j]: (f16)W, W = k<128 ? W_ih[c][k] : W_hh[c][k-128]
//   [32768, 65536)   Wlo[kg][c][j]: (f16)(W - (float)(f16)W)   (residual plane)
//   [65536, 67584)   WD[kg][cc][j]: cc<10 dense_W[cc][k]; cc==10 attn_w[k]; else 0
//
// LDS layout (bytes), 40960 total:
//   [0,16384)      A_hi: 32 rows x 256 k x f16, XOR-swizzled 16B chunks
//                  (chunks 0-15 = x half, 16-31 = h half)
//   [16384,32768)  A_lo: same layout (error-compensation plane)
//   [32768,40960)  y: LN output, 32 rows x 128 f16, swizzled
//
// ROUND 12 = ROUND 10 (32x32 MFMA, structurally verified) + ROUND 11's
// Wlo residual plane (removes the f16-W quantization error that sank R10).
#define PLANE_LO 16384
#define Y_OFF    32768
#define WS_LO    32768   // f16-element offset of Wlo region in d_ws
#define WS_D     65536   // f16-element offset of dense/attn region
#define A_ADDR(row, chunk) (((row) << 9) + ((((chunk) ^ ((row) & 15))) << 4))
#define Y_ADDR(row, chunk) (Y_OFF + ((row) << 8) + ((((chunk) ^ ((row) & 15))) << 4))

__device__ __forceinline__ void split8(float4 a, float4 b, f16x8* hi, f16x8* lo) {
    float v[8] = {a.x, a.y, a.z, a.w, b.x, b.y, b.z, b.w};
    f16x8 h, l;
#pragma unroll
    for (int j = 0; j < 8; ++j) {
        _Float16 hh = (_Float16)v[j];
        h[j] = hh;
        l[j] = (_Float16)(v[j] - (float)hh);
    }
    *hi = h; *lo = l;
}

// ---- prep: convert weights to fragment-layout f16 (hi + residual lo) ----
__global__ __launch_bounds__(256, 1)
void grn_prep(const float* __restrict__ W_ih,
              const float* __restrict__ W_hh,
              const float* __restrict__ dense_W,
              const float* __restrict__ attn_w,
              _Float16* __restrict__ wsg)
{
    const int i  = blockIdx.x * 256 + threadIdx.x;   // 0..4095
    const int kg = i & 31;
    const int c  = i >> 5;
    const int k0 = kg << 3;
    const float* src = (k0 < 128) ? (W_ih + c * 128 + k0)
                                  : (W_hh + c * 128 + (k0 - 128));
    float4 w0 = *(const float4*)src;
    float4 w1 = *(const float4*)(src + 4);
    f16x8 whi, wlo;
    split8(w0, w1, &whi, &wlo);
    *(f16x8*)(wsg + kg * 1024 + c * 8)         = whi;
    *(f16x8*)(wsg + WS_LO + kg * 1024 + c * 8) = wlo;

    if (i < 256) {
        const int kg2 = i >> 4;          // 0..15
        const int cc  = i & 15;          // 0..15
        f16x8 d;
#pragma unroll
        for (int j = 0; j < 8; ++j) {
            const int k = (kg2 << 3) + j;
            float v = 0.f;
            if (cc < 10)       v = dense_W[cc * 128 + k];
            else if (cc == 10) v = attn_w[k];
            d[j] = (_Float16)v;
        }
        *(f16x8*)(wsg + WS_D + kg2 * 128 + cc * 8) = d;
    }
}

__global__ __launch_bounds__(NTHREADS, 1)
void grn_r12(const float* __restrict__ X,
             const _Float16* __restrict__ wsg,
             const float* __restrict__ b_ih,
             const float* __restrict__ b_hh,
             const float* __restrict__ gamma,
             const float* __restrict__ beta,
             const float* __restrict__ dense_b,
             float* __restrict__ out)
{
    __shared__ __align__(16) char smem[40960];
    char* smA = smem;

    const int tid  = threadIdx.x;
    const int lane = tid & 63;
    const int wave = tid >> 6;       // 0..3; wave owns cols wave*32..wave*32+31
    const int n0   = blockIdx.x * RPB;

    // ---- W fragments for 32x32x16 (raw 16B loads; hi + lo planes):
    // operand-A of mfma(W, A): W-row c = wave*32 + (lane&31), k = kstep*16 + (lane>>5)*8 + j
    f16x8 Whi[16], Wlo[16];
    {
        const int cW = (wave << 5) + (lane & 31);
#pragma unroll
        for (int kstep = 0; kstep < 16; ++kstep) {
            const int kc = (kstep << 1) + (lane >> 5);
            Whi[kstep] = *(const f16x8*)(wsg + kc * 1024 + cW * 8);
            Wlo[kstep] = *(const f16x8*)(wsg + WS_LO + kc * 1024 + cW * 8);
        }
    }

    // ---- dense+attn fragments for 16x16x32 P5 (raw loads; waves 0,1)
    f16x8 wd[4];
    {
        const int cc = lane & 15;
#pragma unroll
        for (int ks = 0; ks < 4; ++ks) {
            const int kc = (ks << 2) + (lane >> 4);
            wd[ks] = *(const f16x8*)(wsg + WS_D + kc * 128 + cc * 8);
        }
    }

    // ---- bias for the 16 output cols this lane owns (32x32 C/D layout):
    // reg = gq*4+q -> col = wave*32 + gq*8 + (lane>>5)*4 + q
    float4 bias4g[4];
#pragma unroll
    for (int gq = 0; gq < 4; ++gq) {
        const int cb = (wave << 5) + (gq << 3) + ((lane >> 5) << 2);
        float4 bi = *(const float4*)(b_ih + cb);
        float4 bh = *(const float4*)(b_hh + cb);
        bias4g[gq] = make_float4(bi.x + bh.x, bi.y + bh.y, bi.z + bh.z, bi.w + bh.w);
    }

    // ---- LN mapping (R3-proven): 8 lanes per row, 16 cols each
    const int lrow = tid >> 3;   // 0..31
    const int l8   = tid & 7;
    float g[16], bb[16];
    {
        const int cb = l8 << 4;
#pragma unroll
        for (int q = 0; q < 4; ++q) {
            float4 gv = *(const float4*)(gamma + cb + q * 4);
            float4 bv = *(const float4*)(beta  + cb + q * 4);
            g[q*4+0]=gv.x; g[q*4+1]=gv.y; g[q*4+2]=gv.z; g[q*4+3]=gv.w;
            bb[q*4+0]=bv.x; bb[q*4+1]=bv.y; bb[q*4+2]=bv.z; bb[q*4+3]=bv.w;
        }
    }

    // ---- x staging mapping: thread handles rows (tid>>4), (tid>>4)+16, chunk tid&15
    const int xrow = tid >> 4;
    const int xch  = tid & 15;

    // ---- stage x(0) hi/lo, zero h halves of both planes
    {
        const float* xs0 = X + (size_t)(n0 + xrow) * FF + (xch << 3);
        float4 p0 = *(const float4*)xs0;
        float4 p1 = *(const float4*)(xs0 + 4);
        float4 p2 = *(const float4*)(xs0 + 16 * FF);
        float4 p3 = *(const float4*)(xs0 + 16 * FF + 4);
        f16x8 hi, lo;
        split8(p0, p1, &hi, &lo);
        *(f16x8*)(smA + A_ADDR(xrow, xch)) = hi;
        *(f16x8*)(smA + PLANE_LO + A_ADDR(xrow, xch)) = lo;
        split8(p2, p3, &hi, &lo);
        *(f16x8*)(smA + A_ADDR(xrow + 16, xch)) = hi;
        *(f16x8*)(smA + PLANE_LO + A_ADDR(xrow + 16, xch)) = lo;
        f16x8 z;
#pragma unroll
        for (int j = 0; j < 8; ++j) z[j] = (_Float16)0.f;
        // swizzle is a bijection within the h half -> raw clear covers it exactly
        for (int i = tid; i < 1024; i += NTHREADS) {
            const int pl  = i >> 9;
            const int row = (i >> 4) & 31;
            const int ch  = 16 + (i & 15);
            *(f16x8*)(smA + pl * PLANE_LO + (row << 9) + (ch << 4)) = z;
        }
    }
    __syncthreads();

    const int rowA = lane & 31;  // this lane's sample row in the 32x32 output

    // ---- init: h(0) = X[0] @ W_ih^T + b (h halves zero -> full-K fine; NO relu)
    {
        f32x16 acch, accl;
#pragma unroll
        for (int r = 0; r < 16; ++r) { acch[r] = 0.f; accl[r] = 0.f; }
#pragma unroll
        for (int kstep = 0; kstep < 16; ++kstep) {
            const int ch = (kstep << 1) + (lane >> 5);
            f16x8 ah = *(const f16x8*)(smA + A_ADDR(rowA, ch));
            f16x8 al = *(const f16x8*)(smA + PLANE_LO + A_ADDR(rowA, ch));
            acch = __builtin_amdgcn_mfma_f32_32x32x16_f16(Whi[kstep], ah, acch, 0, 0, 0);
            accl = __builtin_amdgcn_mfma_f32_32x32x16_f16(Whi[kstep], al, accl, 0, 0, 0);
            accl = __builtin_amdgcn_mfma_f32_32x32x16_f16(Wlo[kstep], ah, accl, 0, 0, 0);
        }
        __syncthreads();   // zero-h reads done before overwrite
#pragma unroll
        for (int gq = 0; gq < 4; ++gq) {
            const int colb = (wave << 5) + (gq << 3) + ((lane >> 5) << 2);
            f16x4 hi4, lo4;
#pragma unroll
            for (int q = 0; q < 4; ++q) {
                const float v = acch[gq*4+q] + accl[gq*4+q]
                              + ((const float*)&bias4g[gq])[q];
                _Float16 hh = (_Float16)v;
                hi4[q] = hh;
                lo4[q] = (_Float16)(v - (float)hh);
            }
            const int kchw = 16 + (colb >> 3);
            const int addr = (rowA << 9) + ((kchw ^ (rowA & 15)) << 4) + ((colb & 7) << 1);
            *(f16x4*)(smA + addr) = hi4;
            *(f16x4*)(smA + PLANE_LO + addr) = lo4;
        }
    }
    __syncthreads();

    // ---- online softmax state (waves 0,1: 4 row-slots each; class col = lane&15)
    float stm[4], stz[4], sta[4];
#pragma unroll
    for (int s = 0; s < 4; ++s) { stm[s] = -INFINITY; stz[s] = 0.f; sta[s] = 0.f; }

    // ================= time loop (proven order: P2;B;P3;B;P4;B;P5) =================
    for (int t = 0; t < TT; ++t) {
        // prefetch x(t+1) (consumed in P3; overlaps P2)
        float4 p0, p1, p2, p3;
        if (t < TT - 1) {
            const float* xs0 = X + ((size_t)(t + 1) * NN + n0 + xrow) * FF + (xch << 3);
            p0 = *(const float4*)xs0;
            p1 = *(const float4*)(xs0 + 4);
            p2 = *(const float4*)(xs0 + 16 * FF);
            p3 = *(const float4*)(xs0 + 16 * FF + 4);
        }

        // ---- P2: pre = [x|h] @ (Whi+Wlo) via 32x32x16, 3 chains in 2 accumulators
        f32x16 acch, accl;
#pragma unroll
        for (int r = 0; r < 16; ++r) { acch[r] = 0.f; accl[r] = 0.f; }
#pragma unroll
        for (int kstep = 0; kstep < 16; ++kstep) {
            const int ch = (kstep << 1) + (lane >> 5);
            f16x8 ah = *(const f16x8*)(smA + A_ADDR(rowA, ch));
            f16x8 al = *(const f16x8*)(smA + PLANE_LO + A_ADDR(rowA, ch));
            acch = __builtin_amdgcn_mfma_f32_32x32x16_f16(Whi[kstep], ah, acch, 0, 0, 0);
            accl = __builtin_amdgcn_mfma_f32_32x32x16_f16(Whi[kstep], al, accl, 0, 0, 0);
            accl = __builtin_amdgcn_mfma_f32_32x32x16_f16(Wlo[kstep], ah, accl, 0, 0, 0);
        }
        __syncthreads();   // B3: all x(t)/h(t) reads done

        // ---- P3: h(t+1) = relu(pre+bias) -> h half (hi/lo); stage x(t+1) -> x half
#pragma unroll
        for (int gq = 0; gq < 4; ++gq) {
            const int colb = (wave << 5) + (gq << 3) + ((lane >> 5) << 2);
            f16x4 hi4, lo4;
#pragma unroll
            for (int q = 0; q < 4; ++q) {
                const float v = fmaxf(acch[gq*4+q] + accl[gq*4+q]
                                      + ((const float*)&bias4g[gq])[q], 0.f);
                _Float16 hh = (_Float16)v;
                hi4[q] = hh;
                lo4[q] = (_Float16)(v - (float)hh);
            }
            const int kchw = 16 + (colb >> 3);
            const int addr = (rowA << 9) + ((kchw ^ (rowA & 15)) << 4) + ((colb & 7) << 1);
            *(f16x4*)(smA + addr) = hi4;
            *(f16x4*)(smA + PLANE_LO + addr) = lo4;
        }
        if (t < TT - 1) {
            f16x8 hi, lo;
            split8(p0, p1, &hi, &lo);
            *(f16x8*)(smA + A_ADDR(xrow, xch)) = hi;
            *(f16x8*)(smA + PLANE_LO + A_ADDR(xrow, xch)) = lo;
            split8(p2, p3, &hi, &lo);
            *(f16x8*)(smA + A_ADDR(xrow + 16, xch)) = hi;
            *(f16x8*)(smA + PLANE_LO + A_ADDR(xrow + 16, xch)) = lo;
        }
        __syncthreads();   // B4: h(t+1) + x(t+1) visible

        // ---- P4: LN(h(t+1)) = outs[t] -> y (f16)  [R3-proven block]
        {
            f16x8 h0v = *(const f16x8*)(smA + A_ADDR(lrow, 16 + (l8 << 1)));
            f16x8 h1v = *(const f16x8*)(smA + A_ADDR(lrow, 16 + (l8 << 1) + 1));
            float v[16];
            float s1 = 0.f, s2 = 0.f;
#pragma unroll
            for (int j = 0; j < 8; ++j) { v[j] = (float)h0v[j]; v[8 + j] = (float)h1v[j]; }
#pragma unroll
            for (int j = 0; j < 16; ++j) { s1 += v[j]; s2 += v[j] * v[j]; }
            s1 += __shfl_xor(s1, 1); s2 += __shfl_xor(s2, 1);
            s1 += __shfl_xor(s1, 2); s2 += __shfl_xor(s2, 2);
            s1 += __shfl_xor(s1, 4); s2 += __shfl_xor(s2, 4);
            const float mu  = s1 * (1.f / 128.f);
            const float var = s2 * (1.f / 128.f) - mu * mu;
            const float rsi = rsqrtf(var + 1e-5f);
            f16x8 y0, y1;
#pragma unroll
            for (int j = 0; j < 8; ++j)
                y0[j] = (_Float16)((v[j] - mu) * rsi * g[j] + bb[j]);
#pragma unroll
            for (int j = 0; j < 8; ++j)
                y1[j] = (_Float16)((v[8 + j] - mu) * rsi * g[8 + j] + bb[8 + j]);
            *(f16x8*)(smem + Y_ADDR(lrow, (l8 << 1)))     = y0;
            *(f16x8*)(smem + Y_ADDR(lrow, (l8 << 1) + 1)) = y1;
        }
        __syncthreads();   // B5: y visible

        // ---- P5 (waves 0,1): [dense|logit] = y @ B2 (16x16x32) + online softmax
        if (wave < 2) {
            f32x4 acc2 = (f32x4){0.f,0.f,0.f,0.f};
#pragma unroll
            for (int ks = 0; ks < 4; ++ks) {
                const int kc = (ks << 2) + (lane >> 4);
                f16x8 a = *(const f16x8*)(smem + Y_ADDR((wave << 4) + (lane & 15), kc));
                acc2 = __builtin_amdgcn_mfma_f32_16x16x32_f16(a, wd[ks], acc2, 0, 0, 0);
            }
#pragma unroll
            for (int r = 0; r < 4; ++r) {
                const float dval = acc2[r];
                const float lg = __shfl(dval, (lane & 48) + 10);
                const float mn = fmaxf(stm[r], lg);
                const float sc = __expf(stm[r] - mn);   // 0 on first step
                const float e  = __expf(lg - mn);
                stz[r] = stz[r] * sc + e;
                sta[r] = sta[r] * sc + e * dval;
                stm[r] = mn;
            }
        }
        // next iteration's B3/B4 fence P5's y reads against the next P4's y writes
    }

    // ---- epilogue: wave w (0,1) owns rows w*16..w*16+15
    if (wave < 2) {
        const int c = lane & 15;
        if (c < CC) {
            const float db = dense_b[c];
#pragma unroll
            for (int r = 0; r < 4; ++r) {
                const int row = (wave << 4) + ((lane >> 4) << 2) + r;
                out[(size_t)(n0 + row) * CC + c] = sta[r] / stz[r] + db;
            }
        }
    }
}

extern "C" void kernel_launch(void* const* d_in, const int* in_sizes, int n_in,
                              void* d_out, int out_size, void* d_ws, size_t ws_size,
                              hipStream_t stream) {
    const float* X      = (const float*)d_in[0];
    const float* W_ih   = (const float*)d_in[1];
    const float* W_hh   = (const float*)d_in[2];
    const float* b_ih   = (const float*)d_in[3];
    const float* b_hh   = (const float*)d_in[4];
    const float* gamma  = (const float*)d_in[5];
    const float* beta   = (const float*)d_in[6];
    const float* attn_w = (const float*)d_in[7];
    // d_in[8] = attn_b: cancels in softmax (shift invariance) — unused.
    const float* dW     = (const float*)d_in[9];
    const float* db     = (const float*)d_in[10];
    float* out = (float*)d_out;
    _Float16* wsg = (_Float16*)d_ws;
    (void)in_sizes; (void)n_in; (void)out_size; (void)ws_size;

    grn_prep<<<dim3(16), dim3(256), 0, stream>>>(W_ih, W_hh, dW, attn_w, wsg);
    grn_r12<<<dim3(NN / RPB), dim3(NTHREADS), 0, stream>>>(
        X, wsg, b_ih, b_hh, gamma, beta, db, out);
}

// Round 14
// 203.616 us; speedup vs baseline: 1.4401x; 1.4401x over previous
//
#include <hip/hip_runtime.h>
#include <math.h>

// Problem constants (fixed by the reference)
#define TT 32
#define NN 20000
#define FF 128
#define HH 128
#define CC 10
#define RPB 32          // rows per block (20000/32 = 625 blocks exactly)
#define NTHREADS 512    // 8 waves, split 2M x 4N (wave owns 16 rows x 32 cols)

typedef __attribute__((ext_vector_type(8))) _Float16 f16x8;  // 4 VGPRs
typedef __attribute__((ext_vector_type(4))) _Float16 f16x4;  // 2 VGPRs
typedef __attribute__((ext_vector_type(4))) float f32x4;     // MFMA acc

// d_ws layout (f16 elements):
//   [0, 32768)       Whi[kg][c][j]: (f16)W,  W = k<128 ? W_ih[c][k] : W_hh[c][k-128]
//   [32768, 65536)   Wlo[kg][c][j]: (f16)(W - (float)(f16)W)   (residual plane)
//   [65536, 67584)   WD[kg][cc][j]: cc<10 dense_W[cc][k]; cc==10 attn_w[k]; else 0
//
// LDS layout (bytes), 40960 total (identical to R11):
//   [0,16384)      A_hi: 32 rows x 256 k x f16, XOR-swizzled 16B chunks
//                  (chunks 0-15 = x half, 16-31 = h half)
//   [16384,32768)  A_lo: same layout (error-compensation plane)
//   [32768,40960)  y: LN output, 32 rows x 128 f16, swizzled
//
// ROUND 14 = R11 (passing, 211us, 1-ulp) with ONE change: 2M x 4N wave split.
// wm=wave>>2 picks the 16-row half, wn=wave&3 the 32-col stripe. Each wave
// reads only its 16 A-rows -> P2 A-traffic halves (256->128 ds_read_b128 per
// block-step). Sequential 3-barrier schedule (the only passing class) kept
// byte-identical; pipelined variants (R5/R13) are condemned by evidence.
#define PLANE_LO 16384
#define Y_OFF    32768
#define WS_LO    32768   // f16-element offset of Wlo region in d_ws
#define WS_D     65536   // f16-element offset of dense/attn region
#define A_ADDR(row, chunk) (((row) << 9) + ((((chunk) ^ ((row) & 15))) << 4))
#define Y_ADDR(row, chunk) (Y_OFF + ((row) << 8) + ((((chunk) ^ ((row) & 15))) << 4))

__device__ __forceinline__ void split8(float4 a, float4 b, f16x8* hi, f16x8* lo) {
    float v[8] = {a.x, a.y, a.z, a.w, b.x, b.y, b.z, b.w};
    f16x8 h, l;
#pragma unroll
    for (int j = 0; j < 8; ++j) {
        _Float16 hh = (_Float16)v[j];
        h[j] = hh;
        l[j] = (_Float16)(v[j] - (float)hh);
    }
    *hi = h; *lo = l;
}

// ---- prep: convert weights to fragment-layout f16 (hi + residual lo) ----
__global__ __launch_bounds__(256, 1)
void grn_prep(const float* __restrict__ W_ih,
              const float* __restrict__ W_hh,
              const float* __restrict__ dense_W,
              const float* __restrict__ attn_w,
              _Float16* __restrict__ wsg)
{
    const int i  = blockIdx.x * 256 + threadIdx.x;   // 0..4095
    const int kg = i & 31;
    const int c  = i >> 5;
    const int k0 = kg << 3;
    const float* src = (k0 < 128) ? (W_ih + c * 128 + k0)
                                  : (W_hh + c * 128 + (k0 - 128));
    float4 w0 = *(const float4*)src;
    float4 w1 = *(const float4*)(src + 4);
    f16x8 whi, wlo;
    split8(w0, w1, &whi, &wlo);
    *(f16x8*)(wsg + kg * 1024 + c * 8)         = whi;
    *(f16x8*)(wsg + WS_LO + kg * 1024 + c * 8) = wlo;

    if (i < 256) {
        const int kg2 = i >> 4;          // 0..15
        const int cc  = i & 15;          // 0..15
        f16x8 d;
#pragma unroll
        for (int j = 0; j < 8; ++j) {
            const int k = (kg2 << 3) + j;
            float v = 0.f;
            if (cc < 10)       v = dense_W[cc * 128 + k];
            else if (cc == 10) v = attn_w[k];
            d[j] = (_Float16)v;
        }
        *(f16x8*)(wsg + WS_D + kg2 * 128 + cc * 8) = d;
    }
}

__global__ __launch_bounds__(NTHREADS, 1)
void grn_r14(const float* __restrict__ X,
             const _Float16* __restrict__ wsg,
             const float* __restrict__ b_ih,
             const float* __restrict__ b_hh,
             const float* __restrict__ gamma,
             const float* __restrict__ beta,
             const float* __restrict__ dense_b,
             float* __restrict__ out)
{
    __shared__ __align__(16) char smem[40960];
    char* smA = smem;

    const int tid  = threadIdx.x;
    const int lane = tid & 63;
    const int wave = tid >> 6;       // 0..7
    const int wm   = wave >> 2;      // 0,1: row half (rows wm*16 .. wm*16+15)
    const int wn   = wave & 3;       // 0..3: col stripe (cols wn*32 .. wn*32+31)
    const int n0   = blockIdx.x * RPB;

    // ---- W hi+lo stripes into registers via RAW 16B loads (R8-proven path);
    // c = wn*32 + nt*16 + (lane&15), kc = ks*4 + (lane>>4)
    f16x8 Whi[8][2], Wlo[8][2];
#pragma unroll
    for (int ks = 0; ks < 8; ++ks) {
        const int kc = (ks << 2) + (lane >> 4);
#pragma unroll
        for (int nt = 0; nt < 2; ++nt) {
            const int c = (wn << 5) + (nt << 4) + (lane & 15);
            Whi[ks][nt] = *(const f16x8*)(wsg + kc * 1024 + c * 8);
            Wlo[ks][nt] = *(const f16x8*)(wsg + WS_LO + kc * 1024 + c * 8);
        }
    }

    // ---- dense+attn fragments, raw loads (used by waves 0,1)
    f16x8 wd[4];
    {
        const int cc = lane & 15;
#pragma unroll
        for (int ks = 0; ks < 4; ++ks) {
            const int kc = (ks << 2) + (lane >> 4);
            wd[ks] = *(const f16x8*)(wsg + WS_D + kc * 128 + cc * 8);
        }
    }

    // ---- bias float4 per nt (cols this lane owns in swapped layout)
    f32x4 bias4[2];
    int kch[2], c0off[2];
#pragma unroll
    for (int nt = 0; nt < 2; ++nt) {
        const int c0 = (wn << 5) + (nt << 4) + ((lane >> 4) << 2);
        float4 bi = *(const float4*)(b_ih + c0);
        float4 bh = *(const float4*)(b_hh + c0);
        bias4[nt][0] = bi.x + bh.x; bias4[nt][1] = bi.y + bh.y;
        bias4[nt][2] = bi.z + bh.z; bias4[nt][3] = bi.w + bh.w;
        kch[nt]   = 16 + (c0 >> 3);          // h-half chunk for P3 writes
        c0off[nt] = (c0 & 4) << 1;           // byte offset within chunk
    }

    // ---- LN mapping: 16 lanes per row, 8 cols each; gamma/beta in regs
    const int lrow = tid >> 4;   // 0..31
    const int lc   = tid & 15;   // chunk / col-group
    float g[8], bb[8];
    {
        const int cb = lc << 3;
        float4 g0 = *(const float4*)(gamma + cb);
        float4 g1 = *(const float4*)(gamma + cb + 4);
        float4 b0 = *(const float4*)(beta  + cb);
        float4 b1 = *(const float4*)(beta  + cb + 4);
        g[0]=g0.x; g[1]=g0.y; g[2]=g0.z; g[3]=g0.w;
        g[4]=g1.x; g[5]=g1.y; g[6]=g1.z; g[7]=g1.w;
        bb[0]=b0.x; bb[1]=b0.y; bb[2]=b0.z; bb[3]=b0.w;
        bb[4]=b1.x; bb[5]=b1.y; bb[6]=b1.z; bb[7]=b1.w;
    }

    // ---- stage x(0) hi/lo (one row-chunk per thread), zero h halves
    {
        const float* xs0 = X + (size_t)(n0 + lrow) * FF + (lc << 3);
        float4 p0 = *(const float4*)xs0;
        float4 p1 = *(const float4*)(xs0 + 4);
        f16x8 hi, lo;
        split8(p0, p1, &hi, &lo);
        *(f16x8*)(smA + A_ADDR(lrow, lc)) = hi;
        *(f16x8*)(smA + PLANE_LO + A_ADDR(lrow, lc)) = lo;
        f16x8 z;
#pragma unroll
        for (int j = 0; j < 8; ++j) z[j] = (_Float16)0.f;
        // swizzle is a bijection within the h half -> raw clear covers it exactly
        for (int i = tid; i < 1024; i += NTHREADS) {
            const int pl  = i >> 9;
            const int row = (i >> 4) & 31;
            const int ch  = 16 + (i & 15);
            *(f16x8*)(smA + pl * PLANE_LO + (row << 9) + (ch << 4)) = z;
        }
    }
    __syncthreads();

    const int rowA = (wm << 4) + (lane & 15);   // this lane's sample row

    // ---- init: h0 = X[0] @ W_ih^T + b (h halves zero -> full-K fine; NO relu)
    {
        f32x4 acc[2];   // [nt]; swapped layout: lane&15 = sample row, regs = 4 cols
        acc[0] = (f32x4){0.f,0.f,0.f,0.f};
        acc[1] = (f32x4){0.f,0.f,0.f,0.f};
#pragma unroll
        for (int ks = 0; ks < 8; ++ks) {
            const int kc = (ks << 2) + (lane >> 4);
            f16x8 ah = *(const f16x8*)(smA + A_ADDR(rowA, kc));
            f16x8 al = *(const f16x8*)(smA + PLANE_LO + A_ADDR(rowA, kc));
#pragma unroll
            for (int nt = 0; nt < 2; ++nt) {
                acc[nt] = __builtin_amdgcn_mfma_f32_16x16x32_f16(Whi[ks][nt], ah, acc[nt], 0, 0, 0);
                acc[nt] = __builtin_amdgcn_mfma_f32_16x16x32_f16(Whi[ks][nt], al, acc[nt], 0, 0, 0);
                acc[nt] = __builtin_amdgcn_mfma_f32_16x16x32_f16(Wlo[ks][nt], ah, acc[nt], 0, 0, 0);
            }
        }
        __syncthreads();   // all reads of zero-h done before overwrite
#pragma unroll
        for (int nt = 0; nt < 2; ++nt) {
            f16x4 hi4, lo4;
#pragma unroll
            for (int q = 0; q < 4; ++q) {
                const float v = acc[nt][q] + bias4[nt][q];
                _Float16 hh = (_Float16)v;
                hi4[q] = hh;
                lo4[q] = (_Float16)(v - (float)hh);
            }
            const int addr = (rowA << 9) + (((kch[nt] ^ (rowA & 15))) << 4) + c0off[nt];
            *(f16x4*)(smA + addr) = hi4;
            *(f16x4*)(smA + PLANE_LO + addr) = lo4;
        }
    }
    __syncthreads();

    // ---- online softmax state (waves 0,1: 4 row-slots each; class col = lane&15)
    float stm[4], stz[4], sta[4];
#pragma unroll
    for (int s = 0; s < 4; ++s) { stm[s] = -INFINITY; stz[s] = 0.f; sta[s] = 0.f; }

    // ================= time loop (R11-proven order: P2;B;P3;B;P4;B;P5) =================
    for (int t = 0; t < TT; ++t) {
        // prefetch x(t+1) (one row-chunk per thread; overlaps P2)
        float4 p0, p1;
        if (t < TT - 1) {
            const float* xs0 = X + ((size_t)(t + 1) * NN + n0 + lrow) * FF + (lc << 3);
            p0 = *(const float4*)xs0;
            p1 = *(const float4*)(xs0 + 4);
        }

        // ---- P2: pre = [x|h] @ (Whi+Wlo); wave reads ONLY its 16 rows (halved traffic)
        f32x4 acc[2];
        acc[0] = (f32x4){0.f,0.f,0.f,0.f};
        acc[1] = (f32x4){0.f,0.f,0.f,0.f};
#pragma unroll
        for (int ks = 0; ks < 8; ++ks) {
            const int kc = (ks << 2) + (lane >> 4);
            f16x8 ah = *(const f16x8*)(smA + A_ADDR(rowA, kc));
            f16x8 al = *(const f16x8*)(smA + PLANE_LO + A_ADDR(rowA, kc));
#pragma unroll
            for (int nt = 0; nt < 2; ++nt) {
                acc[nt] = __builtin_amdgcn_mfma_f32_16x16x32_f16(Whi[ks][nt], ah, acc[nt], 0, 0, 0);
                acc[nt] = __builtin_amdgcn_mfma_f32_16x16x32_f16(Whi[ks][nt], al, acc[nt], 0, 0, 0);
                acc[nt] = __builtin_amdgcn_mfma_f32_16x16x32_f16(Wlo[ks][nt], ah, acc[nt], 0, 0, 0);
            }
        }
        __syncthreads();   // B3: all x/h reads done

        // ---- P3: h_new = relu(pre + bias) -> h half (hi/lo) + stage x(t+1) -> x half
#pragma unroll
        for (int nt = 0; nt < 2; ++nt) {
            f16x4 hi4, lo4;
#pragma unroll
            for (int q = 0; q < 4; ++q) {
                const float v = fmaxf(acc[nt][q] + bias4[nt][q], 0.f);
                _Float16 hh = (_Float16)v;
                hi4[q] = hh;
                lo4[q] = (_Float16)(v - (float)hh);
            }
            const int addr = (rowA << 9) + (((kch[nt] ^ (rowA & 15))) << 4) + c0off[nt];
            *(f16x4*)(smA + addr) = hi4;
            *(f16x4*)(smA + PLANE_LO + addr) = lo4;
        }
        if (t < TT - 1) {
            f16x8 hi, lo;
            split8(p0, p1, &hi, &lo);
            *(f16x8*)(smA + A_ADDR(lrow, lc)) = hi;
            *(f16x8*)(smA + PLANE_LO + A_ADDR(lrow, lc)) = lo;
        }
        __syncthreads();   // B4: h_new + x(t+1) visible

        // ---- P4: LayerNorm (h hi-plane) -> y f16 into y buffer
        {
            f16x8 hv = *(const f16x8*)(smA + A_ADDR(lrow, 16 + lc));
            float v[8];
            float s1 = 0.f, s2 = 0.f;
#pragma unroll
            for (int j = 0; j < 8; ++j) { v[j] = (float)hv[j]; }
#pragma unroll
            for (int j = 0; j < 8; ++j) { s1 += v[j]; s2 += v[j] * v[j]; }
            s1 += __shfl_xor(s1, 1); s2 += __shfl_xor(s2, 1);
            s1 += __shfl_xor(s1, 2); s2 += __shfl_xor(s2, 2);
            s1 += __shfl_xor(s1, 4); s2 += __shfl_xor(s2, 4);
            s1 += __shfl_xor(s1, 8); s2 += __shfl_xor(s2, 8);
            const float mu  = s1 * (1.f / 128.f);
            const float var = s2 * (1.f / 128.f) - mu * mu;
            const float rsi = rsqrtf(var + 1e-5f);
            f16x8 y;
#pragma unroll
            for (int j = 0; j < 8; ++j)
                y[j] = (_Float16)((v[j] - mu) * rsi * g[j] + bb[j]);
            *(f16x8*)(smem + Y_ADDR(lrow, lc)) = y;
        }
        __syncthreads();   // B5: y visible

        // ---- P5 (waves 0,1 only): [dense|logit] = y @ B2 (M=16/wave, K=128) + softmax
        if (wave < 2) {
            f32x4 acc2 = (f32x4){0.f,0.f,0.f,0.f};
#pragma unroll
            for (int ks = 0; ks < 4; ++ks) {
                const int kc = (ks << 2) + (lane >> 4);
                f16x8 a = *(const f16x8*)(smem + Y_ADDR((wave << 4) + (lane & 15), kc));
                acc2 = __builtin_amdgcn_mfma_f32_16x16x32_f16(a, wd[ks], acc2, 0, 0, 0);
            }
#pragma unroll
            for (int r = 0; r < 4; ++r) {
                const float dval = acc2[r];
                const float lg = __shfl(dval, (lane & 48) + 10);
                const float mn = fmaxf(stm[r], lg);
                const float sc = __expf(stm[r] - mn);   // 0 on first step
                const float e  = __expf(lg - mn);
                stz[r] = stz[r] * sc + e;
                sta[r] = sta[r] * sc + e * dval;
                stm[r] = mn;
            }
        }
        // next iteration's B3 orders P5's y reads against P4(t+1)'s y writes
    }

    // ---- epilogue: wave w (0,1) owns rows w*16..w*16+15
    if (wave < 2) {
        const int c = lane & 15;
        if (c < CC) {
            const float db = dense_b[c];
#pragma unroll
            for (int r = 0; r < 4; ++r) {
                const int row = (wave << 4) + ((lane >> 4) << 2) + r;
                out[(size_t)(n0 + row) * CC + c] = sta[r] / stz[r] + db;
            }
        }
    }
}

extern "C" void kernel_launch(void* const* d_in, const int* in_sizes, int n_in,
                              void* d_out, int out_size, void* d_ws, size_t ws_size,
                              hipStream_t stream) {
    const float* X      = (const float*)d_in[0];
    const float* W_ih   = (const float*)d_in[1];
    const float* W_hh   = (const float*)d_in[2];
    const float* b_ih   = (const float*)d_in[3];
    const float* b_hh   = (const float*)d_in[4];
    const float* gamma  = (const float*)d_in[5];
    const float* beta   = (const float*)d_in[6];
    const float* attn_w = (const float*)d_in[7];
    // d_in[8] = attn_b: cancels in softmax (shift invariance) — unused.
    const float* dW     = (const float*)d_in[9];
    const float* db     = (const float*)d_in[10];
    float* out = (float*)d_out;
    _Float16* wsg = (_Float16*)d_ws;
    (void)in_sizes; (void)n_in; (void)out_size; (void)ws_size;

    grn_prep<<<dim3(16), dim3(256), 0, stream>>>(W_ih, W_hh, dW, attn_w, wsg);
    grn_r14<<<dim3(NN / RPB), dim3(NTHREADS), 0, stream>>>(
        X, wsg, b_ih, b_hh, gamma, beta, db, out);
}